// Round 1
// baseline (735.747 us; speedup 1.0000x reference)
//
#include <hip/hip_runtime.h>

#define N_NODES 50000
#define N_EDGES 800000
#define HID 128

// ---------------- CSR build ----------------
__global__ void hist_kernel(const int* __restrict__ dst, int* __restrict__ counts) {
    int e = blockIdx.x * 256 + threadIdx.x;
    if (e < N_EDGES) atomicAdd(&counts[dst[e]], 1);
}

__global__ void scan_block_kernel(const int* __restrict__ counts, int* __restrict__ excl,
                                  int* __restrict__ blockSums) {
    __shared__ int s[512];
    int t = threadIdx.x;
    int i = blockIdx.x * 512 + t;
    int v = (i < N_NODES) ? counts[i] : 0;
    s[t] = v;
    __syncthreads();
    for (int off = 1; off < 512; off <<= 1) {
        int add = (t >= off) ? s[t - off] : 0;
        __syncthreads();
        s[t] += add;
        __syncthreads();
    }
    if (i < N_NODES) excl[i] = s[t] - v;
    if (t == 511) blockSums[blockIdx.x] = s[511];
}

__global__ void scan_sums_kernel(const int* __restrict__ blockSums, int* __restrict__ blockOff,
                                 int nb) {
    __shared__ int s[128];
    int t = threadIdx.x;
    int v = (t < nb) ? blockSums[t] : 0;
    s[t] = v;
    __syncthreads();
    for (int off = 1; off < 128; off <<= 1) {
        int add = (t >= off) ? s[t - off] : 0;
        __syncthreads();
        s[t] += add;
        __syncthreads();
    }
    if (t < nb) blockOff[t] = s[t] - v;
}

__global__ void add_off_kernel(int* __restrict__ excl, const int* __restrict__ blockOff) {
    int i = blockIdx.x * 256 + threadIdx.x;
    if (i < N_NODES) excl[i] += blockOff[i >> 9];
}

__global__ void scatter_kernel(const int* __restrict__ src, const int* __restrict__ dst,
                               const int* __restrict__ row_start, int* __restrict__ cursor,
                               int* __restrict__ col) {
    int e = blockIdx.x * 256 + threadIdx.x;
    if (e < N_EDGES) {
        int d = dst[e];
        int p = atomicAdd(&cursor[d], 1);
        col[row_start[d] + p] = src[e];
    }
}

// ---------------- embedding ----------------
__global__ void embed_kernel(const int* __restrict__ feats, const float* __restrict__ key_emb,
                             const float* __restrict__ val_emb, float* __restrict__ h) {
    int idx = blockIdx.x * 256 + threadIdx.x;   // one float4 of one node row
    if (idx >= N_NODES * 32) return;
    int n = idx >> 5, q = idx & 31;
    int f0 = feats[2 * n], f1 = feats[2 * n + 1];
    float4 a = ((const float4*)key_emb)[f0 * 32 + q];
    float4 b = ((const float4*)val_emb)[f1 * 32 + q];
    float4 r;
    r.x = fmaxf(a.x + b.x, 0.f);
    r.y = fmaxf(a.y + b.y, 0.f);
    r.z = fmaxf(a.z + b.z, 0.f);
    r.w = fmaxf(a.w + b.w, 0.f);
    ((float4*)h)[idx] = r;
}

// ---------------- GIN aggregation: z = h + sum_{u in N(n)} h[u] ----------------
// one wave per node; lane covers 2 floats (float2) of the 128-wide row
__global__ __launch_bounds__(256) void agg_kernel(const float* __restrict__ h,
                                                  float* __restrict__ z,
                                                  const int* __restrict__ row_start,
                                                  const int* __restrict__ counts,
                                                  const int* __restrict__ col) {
    int node = blockIdx.x * 4 + (threadIdx.x >> 6);
    if (node >= N_NODES) return;
    int lane = threadIdx.x & 63;
    const float2* hp = (const float2*)h;
    float2 acc = hp[node * 64 + lane];
    int s = row_start[node];
    int c = counts[node];
    for (int j = 0; j < c; ++j) {
        int u = col[s + j];
        float2 v = hp[u * 64 + lane];
        acc.x += v.x;
        acc.y += v.y;
    }
    ((float2*)z)[node * 64 + lane] = acc;
}

// ---------------- fused 2-layer MLP: h = relu(z@W1^T + b1)@W2^T + b2 ----------------
// 128-row tile in LDS; thread = 2 columns x 32 rows register block
__global__ __launch_bounds__(256) void mlp_kernel(const float* __restrict__ zin,
                                                  float* __restrict__ hout,
                                                  const float* __restrict__ W1,
                                                  const float* __restrict__ b1,
                                                  const float* __restrict__ W2,
                                                  const float* __restrict__ b2) {
    __shared__ float zt[128][128];   // 64 KB
    int t = threadIdx.x;
    int row0 = blockIdx.x * 128;
    int maxr = N_NODES - row0;
    if (maxr > 128) maxr = 128;

    // stage z tile (zero-pad past end)
    {
        const float4* zin4 = (const float4*)(zin + (size_t)row0 * HID);
        float4* zt4 = (float4*)&zt[0][0];
        for (int i = t; i < 128 * 32; i += 256) {
            int r = i >> 5;
            float4 v = make_float4(0.f, 0.f, 0.f, 0.f);
            if (r < maxr) v = zin4[i];
            zt4[i] = v;
        }
    }
    __syncthreads();

    int c2 = (t & 63) * 2;   // this thread's 2 columns
    int rg = t >> 6;         // row group (32 rows each); uniform per wave
    float acc0[32], acc1[32];

    // ---- phase 1: z1 = relu(z @ W1^T + b1) ----
    {
        const float4* Wa = (const float4*)(W1 + (size_t)c2 * HID);
        const float4* Wb = (const float4*)(W1 + (size_t)(c2 + 1) * HID);
        float ba = b1[c2], bb = b1[c2 + 1];
#pragma unroll
        for (int r = 0; r < 32; ++r) { acc0[r] = ba; acc1[r] = bb; }
        for (int k4 = 0; k4 < 32; ++k4) {
            float4 wa = Wa[k4];
            float4 wb = Wb[k4];
#pragma unroll
            for (int r = 0; r < 32; ++r) {
                float4 zv = *(const float4*)&zt[rg * 32 + r][k4 * 4];
                acc0[r] += zv.x * wa.x + zv.y * wa.y + zv.z * wa.z + zv.w * wa.w;
                acc1[r] += zv.x * wb.x + zv.y * wb.y + zv.z * wb.z + zv.w * wb.w;
            }
        }
    }
    __syncthreads();
    // write z1 = relu(acc) back into zt
#pragma unroll
    for (int r = 0; r < 32; ++r) {
        float2 v;
        v.x = fmaxf(acc0[r], 0.f);
        v.y = fmaxf(acc1[r], 0.f);
        *(float2*)&zt[rg * 32 + r][c2] = v;
    }
    __syncthreads();

    // ---- phase 2: h = z1 @ W2^T + b2 ----
    {
        const float4* Wa = (const float4*)(W2 + (size_t)c2 * HID);
        const float4* Wb = (const float4*)(W2 + (size_t)(c2 + 1) * HID);
        float ba = b2[c2], bb = b2[c2 + 1];
#pragma unroll
        for (int r = 0; r < 32; ++r) { acc0[r] = ba; acc1[r] = bb; }
        for (int k4 = 0; k4 < 32; ++k4) {
            float4 wa = Wa[k4];
            float4 wb = Wb[k4];
#pragma unroll
            for (int r = 0; r < 32; ++r) {
                float4 zv = *(const float4*)&zt[rg * 32 + r][k4 * 4];
                acc0[r] += zv.x * wa.x + zv.y * wa.y + zv.z * wa.z + zv.w * wa.w;
                acc1[r] += zv.x * wb.x + zv.y * wb.y + zv.z * wb.z + zv.w * wb.w;
            }
        }
    }
#pragma unroll
    for (int r = 0; r < 32; ++r) {
        int rr = rg * 32 + r;
        if (rr < maxr) {
            float2 v;
            v.x = acc0[r];
            v.y = acc1[r];
            *(float2*)&hout[(size_t)(row0 + rr) * HID + c2] = v;
        }
    }
}

// ---------------- classifier: out = h @ Wc^T  (Wc: 40x128) ----------------
__global__ __launch_bounds__(256) void cls_kernel(const float* __restrict__ h,
                                                  const float* __restrict__ Wc,
                                                  float* __restrict__ out) {
    __shared__ float wc[40 * 128];   // 20.5 KB
    int t = threadIdx.x;
    for (int i = t; i < 40 * 32; i += 256)
        ((float4*)wc)[i] = ((const float4*)Wc)[i];
    __syncthreads();
    int node = blockIdx.x * 32 + (t >> 3);
    int og = t & 7;   // 5 output columns per thread
    if (node >= N_NODES) return;
    float acc[5] = {0.f, 0.f, 0.f, 0.f, 0.f};
    const float4* hr = (const float4*)(h + (size_t)node * HID);
    for (int k4 = 0; k4 < 32; ++k4) {
        float4 zv = hr[k4];
#pragma unroll
        for (int i = 0; i < 5; ++i) {
            float4 w = *(const float4*)&wc[(og * 5 + i) * 128 + k4 * 4];
            acc[i] += zv.x * w.x + zv.y * w.y + zv.z * w.z + zv.w * w.w;
        }
    }
#pragma unroll
    for (int i = 0; i < 5; ++i) out[(size_t)node * 40 + og * 5 + i] = acc[i];
}

extern "C" void kernel_launch(void* const* d_in, const int* in_sizes, int n_in,
                              void* d_out, int out_size, void* d_ws, size_t ws_size,
                              hipStream_t stream) {
    const int* feats = (const int*)d_in[0];
    const int* src = (const int*)d_in[1];
    const int* dst = (const int*)d_in[2];
    const float* key_emb = (const float*)d_in[3];
    const float* val_emb = (const float*)d_in[4];
    const float* W1 = (const float*)d_in[5];
    const float* b1 = (const float*)d_in[6];
    const float* W2 = (const float*)d_in[7];
    const float* b2 = (const float*)d_in[8];
    const float* Wc = (const float*)d_in[9];
    float* out = (float*)d_out;

    char* ws = (char*)d_ws;
    auto carve = [&](size_t bytes) {
        char* p = ws;
        ws += (bytes + 255) & ~(size_t)255;
        return p;
    };
    float* h = (float*)carve((size_t)N_NODES * HID * 4);
    float* z = (float*)carve((size_t)N_NODES * HID * 4);
    int* counts = (int*)carve((size_t)N_NODES * 4);
    int* row_start = (int*)carve((size_t)N_NODES * 4);
    int* cursor = (int*)carve((size_t)N_NODES * 4);
    int* blockSums = (int*)carve(256 * 4);
    int* blockOff = (int*)carve(256 * 4);
    int* col = (int*)carve((size_t)N_EDGES * 4);

    hipMemsetAsync(counts, 0, (size_t)N_NODES * 4, stream);
    hipMemsetAsync(cursor, 0, (size_t)N_NODES * 4, stream);

    const int NB_SCAN = (N_NODES + 511) / 512;   // 98
    hist_kernel<<<(N_EDGES + 255) / 256, 256, 0, stream>>>(dst, counts);
    scan_block_kernel<<<NB_SCAN, 512, 0, stream>>>(counts, row_start, blockSums);
    scan_sums_kernel<<<1, 128, 0, stream>>>(blockSums, blockOff, NB_SCAN);
    add_off_kernel<<<(N_NODES + 255) / 256, 256, 0, stream>>>(row_start, blockOff);
    scatter_kernel<<<(N_EDGES + 255) / 256, 256, 0, stream>>>(src, dst, row_start, cursor, col);

    embed_kernel<<<(N_NODES * 32 + 255) / 256, 256, 0, stream>>>(feats, key_emb, val_emb, h);

    for (int l = 0; l < 3; ++l) {
        agg_kernel<<<(N_NODES + 3) / 4, 256, 0, stream>>>(h, z, row_start, counts, col);
        mlp_kernel<<<(N_NODES + 127) / 128, 256, 0, stream>>>(
            z, h, W1 + (size_t)l * HID * HID, b1 + (size_t)l * HID,
            W2 + (size_t)l * HID * HID, b2 + (size_t)l * HID);
    }
    cls_kernel<<<(N_NODES + 31) / 32, 256, 0, stream>>>(h, Wc, out);
}